// Round 2
// baseline (553.898 us; speedup 1.0000x reference)
//
#include <hip/hip_runtime.h>
#include <stdint.h>

typedef unsigned short u16;
typedef __attribute__((ext_vector_type(8))) short bf16x8;
typedef __attribute__((ext_vector_type(4))) float f32x4;

#define MFMA16(a, b, c) __builtin_amdgcn_mfma_f32_16x16x32_bf16((a), (b), (c), 0, 0, 0)

__device__ __forceinline__ float b2f(u16 u) {
    union { unsigned int i; float f; } v; v.i = ((unsigned int)u) << 16; return v.f;
}
__device__ __forceinline__ u16 f2b(float f) {
    union { float f; unsigned int i; } v; v.f = f;
    unsigned int r = v.i + 0x7fffu + ((v.i >> 16) & 1u);
    return (u16)(r >> 16);
}
__device__ __forceinline__ unsigned int pack2(float a, float b) {
    return (unsigned int)f2b(a) | ((unsigned int)f2b(b) << 16);
}

typedef __attribute__((address_space(1))) void gvoid;
typedef __attribute__((address_space(3))) void lvoid;
__device__ __forceinline__ void gld16(const void* g, void* l) {
    __builtin_amdgcn_global_load_lds((gvoid*)(void*)g, (lvoid*)l, 16, 0, 0);
}

// ---------------------------------------------------------------------------
// fp32 -> bf16 elementwise convert (n multiple of 4)
// ---------------------------------------------------------------------------
__global__ __launch_bounds__(256) void f32_to_bf16(const float* __restrict__ in,
                                                   u16* __restrict__ out, int n) {
    const int i = (blockIdx.x * 256 + threadIdx.x) * 4;
    if (i + 3 < n) {
        const float4 v = *(const float4*)(in + i);
        ushort4 o;
        o.x = f2b(v.x); o.y = f2b(v.y); o.z = f2b(v.z); o.w = f2b(v.w);
        *(ushort4*)(out + i) = o;
    }
}

// ---------------------------------------------------------------------------
// fused transpose + fp32->bf16: out[C x R](bf16) = in[R x C](f32)^T
// R, C multiples of 32
// ---------------------------------------------------------------------------
__global__ __launch_bounds__(256) void transpose_f32_bf16(const float* __restrict__ in,
                                                          u16* __restrict__ out,
                                                          int R, int C) {
    __shared__ float tile[32][33];
    const int t = threadIdx.x;
    const int r = t >> 3, c4 = (t & 7) * 4;
    const int ir = blockIdx.y * 32 + r, ic = blockIdx.x * 32 + c4;
    const float4 v = *(const float4*)(in + (size_t)ir * C + ic);
    tile[r][c4 + 0] = v.x; tile[r][c4 + 1] = v.y;
    tile[r][c4 + 2] = v.z; tile[r][c4 + 3] = v.w;
    __syncthreads();
    const int orow = blockIdx.x * 32 + r, ocol = blockIdx.y * 32 + c4;
    ushort4 o;
    o.x = f2b(tile[c4 + 0][r]); o.y = f2b(tile[c4 + 1][r]);
    o.z = f2b(tile[c4 + 2][r]); o.w = f2b(tile[c4 + 3][r]);
    *(ushort4*)(out + (size_t)orow * R + ocol) = o;
}

// ---------------------------------------------------------------------------
// C[M x N] = A[M x K](bf16) * Bt[N x K](bf16)^T + bias[N](f32)
// out bf16 (F32OUT=false) or f32 (F32OUT=true); fp32 accumulation.
// 128x128 tile, BK=32, 256 threads (4 waves, each 64x64), global_load_lds.
// LDS "chunk" layout: chunk c holds row ((c>>6)*16 + (c&15)), k-chunk
// ((c>>4)&3) -> staging is exactly base + lane*16 per wave (global_load_lds
// constraint) and fragment ds_read_b128 are 2-way banks max.
// ---------------------------------------------------------------------------
template <bool F32OUT>
__global__ __launch_bounds__(256) void gemm_bt(const u16* __restrict__ A,
                                               const u16* __restrict__ Bt,
                                               const float* __restrict__ bias,
                                               void* __restrict__ Cv,
                                               int M, int N, int K) {
    __shared__ __align__(16) u16 As[128 * 32];
    __shared__ __align__(16) u16 Bs[128 * 32];

    const int t = threadIdx.x;
    const int lane = t & 63, wave = t >> 6;
    const int l15 = lane & 15, quad = lane >> 4;
    const int wm = wave >> 1, wn = wave & 1;
    const int row0 = blockIdx.x * 128;
    const int col0 = blockIdx.y * 128;

    const f32x4 fz = {0.f, 0.f, 0.f, 0.f};
    f32x4 acc[4][4];
#pragma unroll
    for (int i = 0; i < 4; ++i)
#pragma unroll
        for (int j = 0; j < 4; ++j) acc[i][j] = fz;

    const int c0 = t, c1 = t + 256;
    const int r0c = ((c0 >> 6) << 4) + (c0 & 15), k0c = (c0 >> 4) & 3;
    const int r1c = ((c1 >> 6) << 4) + (c1 & 15), k1c = (c1 >> 4) & 3;
    int ar0 = row0 + r0c; if (ar0 > M - 1) ar0 = M - 1;   // clamp last partial M tile
    int ar1 = row0 + r1c; if (ar1 > M - 1) ar1 = M - 1;
    const int br0 = col0 + r0c, br1 = col0 + r1c;          // N is a multiple of 128
    const u16* Ap0 = A + (size_t)ar0 * K + k0c * 8;
    const u16* Ap1 = A + (size_t)ar1 * K + k1c * 8;
    const u16* Bp0 = Bt + (size_t)br0 * K + k0c * 8;
    const u16* Bp1 = Bt + (size_t)br1 * K + k1c * 8;
    u16* Al0 = As + c0 * 8; u16* Al1 = As + c1 * 8;
    u16* Bl0 = Bs + c0 * 8; u16* Bl1 = Bs + c1 * 8;

    const int nKT = K >> 5;
    for (int kt = 0; kt < nKT; ++kt) {
        __syncthreads();
        const int kb = kt << 5;
        gld16(Ap0 + kb, Al0);
        gld16(Ap1 + kb, Al1);
        gld16(Bp0 + kb, Bl0);
        gld16(Bp1 + kb, Bl1);
        __syncthreads();
        bf16x8 af[4], bfr[4];
#pragma unroll
        for (int mi = 0; mi < 4; ++mi)
            af[mi] = *(const bf16x8*)(As + ((wm * 4 + mi) * 64 + quad * 16 + l15) * 8);
#pragma unroll
        for (int ni = 0; ni < 4; ++ni)
            bfr[ni] = *(const bf16x8*)(Bs + ((wn * 4 + ni) * 64 + quad * 16 + l15) * 8);
#pragma unroll
        for (int mi = 0; mi < 4; ++mi)
#pragma unroll
            for (int ni = 0; ni < 4; ++ni)
                acc[mi][ni] = MFMA16(af[mi], bfr[ni], acc[mi][ni]);
    }

#pragma unroll
    for (int ni = 0; ni < 4; ++ni) {
        const int col = col0 + wn * 64 + ni * 16 + l15;
        const float bv = bias[col];
#pragma unroll
        for (int mi = 0; mi < 4; ++mi) {
#pragma unroll
            for (int r = 0; r < 4; ++r) {
                const int row = row0 + wm * 64 + mi * 16 + quad * 4 + r;
                if (row < M) {
                    const float val = acc[mi][ni][r] + bv;
                    if (F32OUT) ((float*)Cv)[(size_t)row * N + col] = val;
                    else        ((u16*)Cv)[(size_t)row * N + col] = f2b(val);
                }
            }
        }
    }
}

// ---------------------------------------------------------------------------
// Attention: one block = one (b, h, 16-query-row tile). RoPE fused into Q/K
// staging. S (16 x 644 fp32) in LDS, two-pass softmax, PV with on-the-fly
// exp->bf16 A-fragments. 64-key tiles. LDS = 62,080 B -> 2 blocks/CU.
// qkv (bf16) layout: row (b*577+n), col = which*768 + h*64 + d.
// cos/sin are fp32 (577-1, 32).
// ---------------------------------------------------------------------------
#define SSTR 644  // 640 padded keys + 4 (stride % 32 == 4 -> 2-way banks)

__global__ __launch_bounds__(256) void attn(const u16* __restrict__ qkv,
                                            const float* __restrict__ cosp,
                                            const float* __restrict__ sinp,
                                            u16* __restrict__ aout) {
    __shared__ __align__(16) float S[16 * SSTR];
    __shared__ __align__(16) u16 Qs[16 * 72];
    __shared__ __align__(16) u16 Ks[64 * 72];
    __shared__ __align__(16) u16 Vt[64 * 72];
    __shared__ float mrow[16], lrow[16];

    const int t = threadIdx.x;
    const int lane = t & 63, wave = t >> 6;
    const int l15 = lane & 15, quad = lane >> 4;
    const int qt = blockIdx.x;          // 0..36 (16 query rows each)
    const int bh = blockIdx.y;          // 0..191
    const int b = bh / 12, h = bh % 12;
    const int q0 = qt * 16;
    const u16* base = qkv + (size_t)b * 577 * 2304 + h * 64;

    // ---- Q tile (16 rows) with RoPE: 4 elements / thread ----
    {
        const int r = t >> 4, dd = (t & 15) * 4;
        const int n = q0 + r;
        float v[4];
        if (n < 577) {
            const uint2 raw = *(const uint2*)(base + (size_t)n * 2304 + dd);
            v[0] = b2f((u16)(raw.x & 0xffffu)); v[1] = b2f((u16)(raw.x >> 16));
            v[2] = b2f((u16)(raw.y & 0xffffu)); v[3] = b2f((u16)(raw.y >> 16));
            if (n >= 1) {
                const float2 cc = *(const float2*)(cosp + (size_t)(n - 1) * 32 + (dd >> 1));
                const float2 ss = *(const float2*)(sinp + (size_t)(n - 1) * 32 + (dd >> 1));
                float c = cc.x, s = ss.x, t0 = v[0], t1 = v[1];
                v[0] = t0 * c - t1 * s; v[1] = t0 * s + t1 * c;
                c = cc.y; s = ss.y; t0 = v[2]; t1 = v[3];
                v[2] = t0 * c - t1 * s; v[3] = t0 * s + t1 * c;
            }
        } else {
            v[0] = v[1] = v[2] = v[3] = 0.f;
        }
        uint2 o; o.x = pack2(v[0], v[1]); o.y = pack2(v[2], v[3]);
        *(uint2*)(Qs + r * 72 + dd) = o;
    }
    __syncthreads();

    bf16x8 aq[2];
#pragma unroll
    for (int kk = 0; kk < 2; ++kk)
        aq[kk] = *(const bf16x8*)(Qs + l15 * 72 + kk * 32 + quad * 8);

    // ---- Phase A: S = (Q K^T) * scale, 64-key tiles ----
    for (int jt = 0; jt < 10; ++jt) {
        __syncthreads();
        {   // stage 64 keys with RoPE: 16 elements / thread
            const int r = t >> 2, dd = (t & 3) * 16;
            const int n = jt * 64 + r;
            float v[16];
            if (n < 577) {
                const u16* kp = base + 768 + (size_t)n * 2304 + dd;
                const uint4 raw0 = *(const uint4*)(kp);
                const uint4 raw1 = *(const uint4*)(kp + 8);
                const unsigned int w8[8] = {raw0.x, raw0.y, raw0.z, raw0.w,
                                            raw1.x, raw1.y, raw1.z, raw1.w};
#pragma unroll
                for (int j = 0; j < 8; ++j) {
                    v[2 * j]     = b2f((u16)(w8[j] & 0xffffu));
                    v[2 * j + 1] = b2f((u16)(w8[j] >> 16));
                }
                if (n >= 1) {
                    const float* cp = cosp + (size_t)(n - 1) * 32 + (dd >> 1);
                    const float* sp = sinp + (size_t)(n - 1) * 32 + (dd >> 1);
                    const float4 c0 = *(const float4*)cp;
                    const float4 c1 = *(const float4*)(cp + 4);
                    const float4 s0 = *(const float4*)sp;
                    const float4 s1 = *(const float4*)(sp + 4);
                    const float ca[8] = {c0.x, c0.y, c0.z, c0.w, c1.x, c1.y, c1.z, c1.w};
                    const float sa[8] = {s0.x, s0.y, s0.z, s0.w, s1.x, s1.y, s1.z, s1.w};
#pragma unroll
                    for (int p = 0; p < 8; ++p) {
                        const float c = ca[p], s = sa[p];
                        const float t0 = v[2 * p], t1 = v[2 * p + 1];
                        v[2 * p]     = t0 * c - t1 * s;
                        v[2 * p + 1] = t0 * s + t1 * c;
                    }
                }
            } else {
#pragma unroll
                for (int j = 0; j < 16; ++j) v[j] = 0.f;
            }
            uint4 o0, o1;
            o0.x = pack2(v[0], v[1]);   o0.y = pack2(v[2], v[3]);
            o0.z = pack2(v[4], v[5]);   o0.w = pack2(v[6], v[7]);
            o1.x = pack2(v[8], v[9]);   o1.y = pack2(v[10], v[11]);
            o1.z = pack2(v[12], v[13]); o1.w = pack2(v[14], v[15]);
            *(uint4*)(Ks + r * 72 + dd) = o0;
            *(uint4*)(Ks + r * 72 + dd + 8) = o1;
        }
        __syncthreads();
        // each wave: one 16x16 S tile (keys wave*16 within this 64-key tile)
        f32x4 sacc = {0.f, 0.f, 0.f, 0.f};
#pragma unroll
        for (int kk = 0; kk < 2; ++kk) {
            const bf16x8 bk = *(const bf16x8*)(Ks + (wave * 16 + l15) * 72 + kk * 32 + quad * 8);
            sacc = MFMA16(aq[kk], bk, sacc);
        }
        const int colk = jt * 64 + wave * 16 + l15;
        const bool valid = (colk < 577);
        float* sp = S + (quad * 4) * SSTR + colk;
#pragma unroll
        for (int r = 0; r < 4; ++r)
            sp[r * SSTR] = valid ? sacc[r] * 0.125f : -1e30f;
    }
    __syncthreads();

    // ---- softmax stats: 16 rows x 16 threads ----
    {
        const int r = t >> 4, cs = t & 15;
        const float* sr = S + r * SSTR;
        float mx = -1e30f;
        for (int c = cs; c < 640; c += 16) mx = fmaxf(mx, sr[c]);
#pragma unroll
        for (int off = 8; off >= 1; off >>= 1) mx = fmaxf(mx, __shfl_xor(mx, off));
        float sum = 0.f;
        for (int c = cs; c < 640; c += 16) sum += __expf(sr[c] - mx);
#pragma unroll
        for (int off = 8; off >= 1; off >>= 1) sum += __shfl_xor(sum, off);
        if (cs == 0) { mrow[r] = mx; lrow[r] = 1.f / sum; }
    }
    __syncthreads();
    const float mr = mrow[l15];

    // ---- Phase B: O = exp(S - m) * V, rescale by 1/l at store ----
    f32x4 oacc = {0.f, 0.f, 0.f, 0.f};
    for (int jt = 0; jt < 10; ++jt) {
        __syncthreads();
        {   // stage 64 V rows transposed: Vt[d][key], key stride 72
            const int r = t >> 2, dd = (t & 3) * 16;
            const int n = jt * 64 + r;
            u16 u[16];
            if (n < 577) {
                const u16* vp = base + 1536 + (size_t)n * 2304 + dd;
                const uint4 raw0 = *(const uint4*)(vp);
                const uint4 raw1 = *(const uint4*)(vp + 8);
                const unsigned int w8[8] = {raw0.x, raw0.y, raw0.z, raw0.w,
                                            raw1.x, raw1.y, raw1.z, raw1.w};
#pragma unroll
                for (int j = 0; j < 8; ++j) {
                    u[2 * j] = (u16)(w8[j] & 0xffffu);
                    u[2 * j + 1] = (u16)(w8[j] >> 16);
                }
            } else {
#pragma unroll
                for (int j = 0; j < 16; ++j) u[j] = 0;
            }
#pragma unroll
            for (int j = 0; j < 16; ++j) Vt[(dd + j) * 72 + r] = u[j];
        }
        __syncthreads();
#pragma unroll
        for (int kk = 0; kk < 2; ++kk) {
            const float* srp = S + l15 * SSTR + jt * 64 + kk * 32 + quad * 8;
            bf16x8 pf;
#pragma unroll
            for (int j = 0; j < 8; ++j) ((u16*)&pf)[j] = f2b(__expf(srp[j] - mr));
            const bf16x8 vf = *(const bf16x8*)(Vt + (wave * 16 + l15) * 72 + kk * 32 + quad * 8);
            oacc = MFMA16(pf, vf, oacc);
        }
    }

    // ---- store: out rows quad*4+r, d = wave*16 + l15 ----
    {
        const int d = wave * 16 + l15;
#pragma unroll
        for (int r = 0; r < 4; ++r) {
            const int rr = quad * 4 + r;
            const int n = q0 + rr;
            if (n < 577)
                aout[((size_t)b * 577 + n) * 768 + h * 64 + d] = f2b(oacc[r] * lrow[rr]);
        }
    }
}

// ---------------------------------------------------------------------------
// Launch: convert x -> bf16; transpose+convert weights; GEMM1 (qkv, bf16);
// attention (bf16); GEMM2 (proj, fp32 out).
// Workspace (bytes): xb 14,180,352 | wqkvT 3,538,944 | wprojT 1,179,648 |
//                    qkv 42,541,056 | aout 14,180,352  = 75,620,352 total.
// ---------------------------------------------------------------------------
extern "C" void kernel_launch(void* const* d_in, const int* in_sizes, int n_in,
                              void* d_out, int out_size, void* d_ws, size_t ws_size,
                              hipStream_t stream) {
    const float* x      = (const float*)d_in[0];
    const float* cosp   = (const float*)d_in[1];
    const float* sinp   = (const float*)d_in[2];
    const float* w_qkv  = (const float*)d_in[3];
    const float* b_qkv  = (const float*)d_in[4];
    const float* w_proj = (const float*)d_in[5];
    const float* b_proj = (const float*)d_in[6];
    float* out = (float*)d_out;

    char* ws = (char*)d_ws;
    u16* xb     = (u16*)(ws);
    u16* wqkvT  = (u16*)(ws + 14180352);
    u16* wprojT = (u16*)(ws + 17719296);
    u16* qkv    = (u16*)(ws + 18898944);
    u16* aout   = (u16*)(ws + 61440000);

    f32_to_bf16<<<6924, 256, 0, stream>>>(x, xb, 7090176);
    transpose_f32_bf16<<<dim3(72, 24), 256, 0, stream>>>(w_qkv, wqkvT, 768, 2304);
    transpose_f32_bf16<<<dim3(24, 24), 256, 0, stream>>>(w_proj, wprojT, 768, 768);
    gemm_bt<false><<<dim3(73, 18), 256, 0, stream>>>(xb, wqkvT, b_qkv, qkv, 9232, 2304, 768);
    attn<<<dim3(37, 192), 256, 0, stream>>>(qkv, cosp, sinp, aout);
    gemm_bt<true><<<dim3(73, 6), 256, 0, stream>>>(aout, wprojT, b_proj, out, 9232, 768, 768);
}

// Round 3
// 314.942 us; speedup vs baseline: 1.7587x; 1.7587x over previous
//
#include <hip/hip_runtime.h>
#include <stdint.h>

typedef unsigned short u16;
typedef __attribute__((ext_vector_type(8))) short bf16x8;
typedef __attribute__((ext_vector_type(4))) float f32x4;

#define MFMA16(a, b, c) __builtin_amdgcn_mfma_f32_16x16x32_bf16((a), (b), (c), 0, 0, 0)

__device__ __forceinline__ float b2f(u16 u) {
    union { unsigned int i; float f; } v; v.i = ((unsigned int)u) << 16; return v.f;
}
__device__ __forceinline__ u16 f2b(float f) {
    union { float f; unsigned int i; } v; v.f = f;
    unsigned int r = v.i + 0x7fffu + ((v.i >> 16) & 1u);
    return (u16)(r >> 16);
}
__device__ __forceinline__ unsigned int pack2(float a, float b) {
    return (unsigned int)f2b(a) | ((unsigned int)f2b(b) << 16);
}

typedef __attribute__((address_space(1))) void gvoid;
typedef __attribute__((address_space(3))) void lvoid;
__device__ __forceinline__ void gld16(const void* g, void* l) {
    __builtin_amdgcn_global_load_lds((gvoid*)(void*)g, (lvoid*)l, 16, 0, 0);
}

// ---------------------------------------------------------------------------
// fp32 -> bf16 elementwise convert (n multiple of 4)
// ---------------------------------------------------------------------------
__global__ __launch_bounds__(256) void f32_to_bf16(const float* __restrict__ in,
                                                   u16* __restrict__ out, int n) {
    const int i = (blockIdx.x * 256 + threadIdx.x) * 4;
    if (i + 3 < n) {
        const float4 v = *(const float4*)(in + i);
        ushort4 o;
        o.x = f2b(v.x); o.y = f2b(v.y); o.z = f2b(v.z); o.w = f2b(v.w);
        *(ushort4*)(out + i) = o;
    }
}

// ---------------------------------------------------------------------------
// fused transpose + fp32->bf16: out[C x R](bf16) = in[R x C](f32)^T
// ---------------------------------------------------------------------------
__global__ __launch_bounds__(256) void transpose_f32_bf16(const float* __restrict__ in,
                                                          u16* __restrict__ out,
                                                          int R, int C) {
    __shared__ float tile[32][33];
    const int t = threadIdx.x;
    const int r = t >> 3, c4 = (t & 7) * 4;
    const int ir = blockIdx.y * 32 + r, ic = blockIdx.x * 32 + c4;
    const float4 v = *(const float4*)(in + (size_t)ir * C + ic);
    tile[r][c4 + 0] = v.x; tile[r][c4 + 1] = v.y;
    tile[r][c4 + 2] = v.z; tile[r][c4 + 3] = v.w;
    __syncthreads();
    const int orow = blockIdx.x * 32 + r, ocol = blockIdx.y * 32 + c4;
    ushort4 o;
    o.x = f2b(tile[c4 + 0][r]); o.y = f2b(tile[c4 + 1][r]);
    o.z = f2b(tile[c4 + 2][r]); o.w = f2b(tile[c4 + 3][r]);
    *(ushort4*)(out + (size_t)orow * R + ocol) = o;
}

// ---------------------------------------------------------------------------
// In-place RoPE on the q,k sections of qkv (cols 0..1535), tokens n>=1.
// 8 elements (4 interleaved pairs) per thread.
// ---------------------------------------------------------------------------
__global__ __launch_bounds__(256) void rope_qk(u16* __restrict__ qkv,
                                               const float* __restrict__ cosp,
                                               const float* __restrict__ sinp) {
    const int g = blockIdx.x * 256 + threadIdx.x;   // 16*576*192 total
    const int bn = g / 192, ch = g - bn * 192;
    const int b = bn / 576, n = (bn - b * 576) + 1;
    const int col = ch * 8;
    const int d = col & 63;
    u16* p = qkv + ((size_t)b * 577 + n) * 2304 + col;
    const uint4 raw = *(const uint4*)p;
    const float4 c = *(const float4*)(cosp + (size_t)(n - 1) * 32 + (d >> 1));
    const float4 s = *(const float4*)(sinp + (size_t)(n - 1) * 32 + (d >> 1));
    const unsigned int w[4] = {raw.x, raw.y, raw.z, raw.w};
    const float ca[4] = {c.x, c.y, c.z, c.w};
    const float sa[4] = {s.x, s.y, s.z, s.w};
    uint4 o;
    unsigned int* op = (unsigned int*)&o;
#pragma unroll
    for (int j = 0; j < 4; ++j) {
        const float t0 = b2f((u16)(w[j] & 0xffffu));
        const float t1 = b2f((u16)(w[j] >> 16));
        op[j] = pack2(t0 * ca[j] - t1 * sa[j], t0 * sa[j] + t1 * ca[j]);
    }
    *(uint4*)p = o;
}

// ---------------------------------------------------------------------------
// V pre-transpose: VtG[bh][d(64)][n(640 padded, zero-filled)] from qkv V
// section. grid (20, 2, 192).
// ---------------------------------------------------------------------------
__global__ __launch_bounds__(256) void transpose_v(const u16* __restrict__ qkv,
                                                   u16* __restrict__ VtG) {
    __shared__ u16 tile[32][36];
    const int t = threadIdx.x;
    const int r = t >> 3, c4 = (t & 7) * 4;
    const int bh = blockIdx.z, b = bh / 12, h = bh - b * 12;
    const int n0 = blockIdx.x * 32, d0 = blockIdx.y * 32;
    const int n = n0 + r;
    ushort4 v = {0, 0, 0, 0};
    if (n < 577)
        v = *(const ushort4*)(qkv + ((size_t)b * 577 + n) * 2304 + 1536 + h * 64 + d0 + c4);
    tile[r][c4 + 0] = v.x; tile[r][c4 + 1] = v.y;
    tile[r][c4 + 2] = v.z; tile[r][c4 + 3] = v.w;
    __syncthreads();
    ushort4 o;
    o.x = tile[c4 + 0][r]; o.y = tile[c4 + 1][r];
    o.z = tile[c4 + 2][r]; o.w = tile[c4 + 3][r];
    *(ushort4*)(VtG + ((size_t)bh * 64 + d0 + r) * 640 + n0 + c4) = o;
}

// ---------------------------------------------------------------------------
// C[M x N] = A[M x K](bf16) * Bt[N x K](bf16)^T + bias[N](f32)
// m97 structure: 128x128 tile, BK=32, global_load_lds w=16, chunked LDS.
// ---------------------------------------------------------------------------
template <bool F32OUT>
__global__ __launch_bounds__(256) void gemm_bt(const u16* __restrict__ A,
                                               const u16* __restrict__ Bt,
                                               const float* __restrict__ bias,
                                               void* __restrict__ Cv,
                                               int M, int N, int K) {
    __shared__ __align__(16) u16 As[128 * 32];
    __shared__ __align__(16) u16 Bs[128 * 32];

    const int t = threadIdx.x;
    const int lane = t & 63, wave = t >> 6;
    const int l15 = lane & 15, quad = lane >> 4;
    const int wm = wave >> 1, wn = wave & 1;
    const int row0 = blockIdx.x * 128;
    const int col0 = blockIdx.y * 128;

    const f32x4 fz = {0.f, 0.f, 0.f, 0.f};
    f32x4 acc[4][4];
#pragma unroll
    for (int i = 0; i < 4; ++i)
#pragma unroll
        for (int j = 0; j < 4; ++j) acc[i][j] = fz;

    const int c0 = t, c1 = t + 256;
    const int r0c = ((c0 >> 6) << 4) + (c0 & 15), k0c = (c0 >> 4) & 3;
    const int r1c = ((c1 >> 6) << 4) + (c1 & 15), k1c = (c1 >> 4) & 3;
    int ar0 = row0 + r0c; if (ar0 > M - 1) ar0 = M - 1;
    int ar1 = row0 + r1c; if (ar1 > M - 1) ar1 = M - 1;
    const int br0 = col0 + r0c, br1 = col0 + r1c;
    const u16* Ap0 = A + (size_t)ar0 * K + k0c * 8;
    const u16* Ap1 = A + (size_t)ar1 * K + k1c * 8;
    const u16* Bp0 = Bt + (size_t)br0 * K + k0c * 8;
    const u16* Bp1 = Bt + (size_t)br1 * K + k1c * 8;
    u16* Al0 = As + c0 * 8; u16* Al1 = As + c1 * 8;
    u16* Bl0 = Bs + c0 * 8; u16* Bl1 = Bs + c1 * 8;

    const int nKT = K >> 5;
    for (int kt = 0; kt < nKT; ++kt) {
        __syncthreads();
        const int kb = kt << 5;
        gld16(Ap0 + kb, Al0);
        gld16(Ap1 + kb, Al1);
        gld16(Bp0 + kb, Bl0);
        gld16(Bp1 + kb, Bl1);
        __syncthreads();
        bf16x8 af[4], bfr[4];
#pragma unroll
        for (int mi = 0; mi < 4; ++mi)
            af[mi] = *(const bf16x8*)(As + ((wm * 4 + mi) * 64 + quad * 16 + l15) * 8);
#pragma unroll
        for (int ni = 0; ni < 4; ++ni)
            bfr[ni] = *(const bf16x8*)(Bs + ((wn * 4 + ni) * 64 + quad * 16 + l15) * 8);
#pragma unroll
        for (int mi = 0; mi < 4; ++mi)
#pragma unroll
            for (int ni = 0; ni < 4; ++ni)
                acc[mi][ni] = MFMA16(af[mi], bfr[ni], acc[mi][ni]);
    }

#pragma unroll
    for (int ni = 0; ni < 4; ++ni) {
        const int col = col0 + wn * 64 + ni * 16 + l15;
        const float bv = bias[col];
#pragma unroll
        for (int mi = 0; mi < 4; ++mi) {
#pragma unroll
            for (int r = 0; r < 4; ++r) {
                const int row = row0 + wm * 64 + mi * 16 + quad * 4 + r;
                if (row < M) {
                    const float val = acc[mi][ni][r] + bv;
                    if (F32OUT) ((float*)Cv)[(size_t)row * N + col] = val;
                    else        ((u16*)Cv)[(size_t)row * N + col] = f2b(val);
                }
            }
        }
    }
}

// ---------------------------------------------------------------------------
// Flash attention: block = (64-query tile, bh). Online softmax, 64-key tiles.
// RoPE pre-applied; V pre-transposed (VtG). K/V staged via global_load_lds
// into chunked LDS layout (conflict-free b128 fragment reads). P round-trips
// through per-wave LDS (stride 80 -> clean 2-way write banks).
// LDS = 8192 + 8192 + 10240 = 26.6 KB.
// ---------------------------------------------------------------------------
#define PSTR 80

__global__ __launch_bounds__(256) void attn2(const u16* __restrict__ qkv,
                                             const u16* __restrict__ VtG,
                                             u16* __restrict__ aout) {
    __shared__ __align__(16) u16 Ks[64 * 64];
    __shared__ __align__(16) u16 Vs[64 * 64];
    __shared__ __align__(16) u16 Pb[4 * 16 * PSTR];

    const int t = threadIdx.x;
    const int lane = t & 63, wave = t >> 6;
    const int l15 = lane & 15, quad = lane >> 4;
    const int qt = blockIdx.x;          // 0..9
    const int bh = blockIdx.y;          // 0..191
    const int b = bh / 12, h = bh - b * 12;
    const u16* baseQ = qkv + (size_t)b * 577 * 2304 + h * 64;
    const u16* baseK = baseQ + 768;
    const u16* vbase = VtG + (size_t)bh * 64 * 640;

    // Q fragments: wave's 16 queries (A[m=l15][k=quad*8+j])
    const int mq = qt * 64 + wave * 16 + l15;
    const int nq = mq < 577 ? mq : 576;
    bf16x8 aq[2];
    aq[0] = *(const bf16x8*)(baseQ + (size_t)nq * 2304 + quad * 8);
    aq[1] = *(const bf16x8*)(baseQ + (size_t)nq * 2304 + 32 + quad * 8);

    // staging decomposition: thread t owns chunks t and t+256 of the 64x64
    // tile; chunk c -> row (c>>7)*16 + (c&15), col-chunk (c>>4)&7.
    const int r15 = t & 15, cc = (t >> 4) & 7, rg0 = t >> 7;
    const int row0 = rg0 * 16 + r15, row1 = row0 + 32;
    u16* kl0 = Ks + t * 8;  u16* kl1 = Ks + (t + 256) * 8;
    u16* vl0 = Vs + t * 8;  u16* vl1 = Vs + (t + 256) * 8;
    const u16* vp0 = vbase + (size_t)row0 * 640 + cc * 8;
    const u16* vp1 = vbase + (size_t)row1 * 640 + cc * 8;

    u16* Pw = Pb + wave * 16 * PSTR;

    f32x4 oacc[4];
    const f32x4 fz = {0.f, 0.f, 0.f, 0.f};
#pragma unroll
    for (int i = 0; i < 4; ++i) oacc[i] = fz;
    float m4[4] = {-1e30f, -1e30f, -1e30f, -1e30f};
    float l4[4] = {0.f, 0.f, 0.f, 0.f};

    for (int kt = 0; kt < 10; ++kt) {
        __syncthreads();
        {
            int n0 = kt * 64 + row0; if (n0 > 576) n0 = 576;
            int n1 = kt * 64 + row1; if (n1 > 576) n1 = 576;
            gld16(baseK + (size_t)n0 * 2304 + cc * 8, kl0);
            gld16(baseK + (size_t)n1 * 2304 + cc * 8, kl1);
            gld16(vp0 + kt * 64, vl0);
            gld16(vp1 + kt * 64, vl1);
        }
        __syncthreads();

        // ---- S = Q K^T (16 queries x 64 keys per wave) ----
        f32x4 sacc[4];
#pragma unroll
        for (int nt = 0; nt < 4; ++nt) {
            sacc[nt] = fz;
#pragma unroll
            for (int kk = 0; kk < 2; ++kk) {
                const bf16x8 bk = *(const bf16x8*)(Ks + (nt * 128 + (kk * 4 + quad) * 16 + l15) * 8);
                sacc[nt] = MFMA16(aq[kk], bk, sacc[nt]);
            }
        }
        // scale + key-validity mask
        float sv[4][4];
#pragma unroll
        for (int nt = 0; nt < 4; ++nt) {
            const int key = kt * 64 + nt * 16 + l15;
            const bool kvalid = key < 577;
#pragma unroll
            for (int r = 0; r < 4; ++r)
                sv[nt][r] = kvalid ? sacc[nt][r] * 0.125f : -1e30f;
        }
        // ---- online softmax update (rows m = quad*4 + r) ----
        float mt[4];
#pragma unroll
        for (int r = 0; r < 4; ++r) {
            mt[r] = fmaxf(fmaxf(sv[0][r], sv[1][r]), fmaxf(sv[2][r], sv[3][r]));
#pragma unroll
            for (int off = 1; off <= 8; off <<= 1)
                mt[r] = fmaxf(mt[r], __shfl_xor(mt[r], off));
        }
        float alpha[4];
#pragma unroll
        for (int r = 0; r < 4; ++r) {
            const float mnew = fmaxf(m4[r], mt[r]);
            alpha[r] = __expf(m4[r] - mnew);
            m4[r] = mnew;
        }
        float lsum[4] = {0.f, 0.f, 0.f, 0.f};
#pragma unroll
        for (int nt = 0; nt < 4; ++nt) {
#pragma unroll
            for (int r = 0; r < 4; ++r) {
                const float p = __expf(sv[nt][r] - m4[r]);
                lsum[r] += p;
                Pw[(quad * 4 + r) * PSTR + nt * 16 + l15] = f2b(p);
            }
        }
#pragma unroll
        for (int r = 0; r < 4; ++r) {
#pragma unroll
            for (int off = 1; off <= 8; off <<= 1)
                lsum[r] += __shfl_xor(lsum[r], off);
            l4[r] = l4[r] * alpha[r] + lsum[r];
        }
#pragma unroll
        for (int dt = 0; dt < 4; ++dt)
#pragma unroll
            for (int r = 0; r < 4; ++r) oacc[dt][r] *= alpha[r];

        __asm__ __volatile__("s_waitcnt lgkmcnt(0)" ::: "memory");

        // ---- O += P V ----
#pragma unroll
        for (int kc = 0; kc < 2; ++kc) {
            const bf16x8 pf = *(const bf16x8*)(Pw + l15 * PSTR + kc * 32 + quad * 8);
#pragma unroll
            for (int dt = 0; dt < 4; ++dt) {
                const bf16x8 vf = *(const bf16x8*)(Vs + (dt * 128 + (kc * 4 + quad) * 16 + l15) * 8);
                oacc[dt] = MFMA16(pf, vf, oacc[dt]);
            }
        }
    }

    // ---- store ----
    float linv[4];
#pragma unroll
    for (int r = 0; r < 4; ++r) linv[r] = 1.f / l4[r];
#pragma unroll
    for (int r = 0; r < 4; ++r) {
        const int n = qt * 64 + wave * 16 + quad * 4 + r;
        if (n < 577) {
            u16* op = aout + ((size_t)b * 577 + n) * 768 + h * 64 + l15;
#pragma unroll
            for (int dt = 0; dt < 4; ++dt)
                op[dt * 16] = f2b(oacc[dt][r] * linv[r]);
        }
    }
}

// ---------------------------------------------------------------------------
// Workspace (75,620,352 B total, same as round 2):
//   region A [0, 17,719,296): xb (14,180,352) + wqkvT (3,538,944) for GEMM1,
//       then REUSED for VtG (15,728,640) after GEMM1 completes.
//   wprojT @ 17,719,296 (1,179,648)
//   qkv    @ 18,898,944 (42,541,056)
//   aout   @ 61,440,000 (14,180,352)
// ---------------------------------------------------------------------------
extern "C" void kernel_launch(void* const* d_in, const int* in_sizes, int n_in,
                              void* d_out, int out_size, void* d_ws, size_t ws_size,
                              hipStream_t stream) {
    const float* x      = (const float*)d_in[0];
    const float* cosp   = (const float*)d_in[1];
    const float* sinp   = (const float*)d_in[2];
    const float* w_qkv  = (const float*)d_in[3];
    const float* b_qkv  = (const float*)d_in[4];
    const float* w_proj = (const float*)d_in[5];
    const float* b_proj = (const float*)d_in[6];
    float* out = (float*)d_out;

    char* ws = (char*)d_ws;
    u16* xb     = (u16*)(ws);
    u16* wqkvT  = (u16*)(ws + 14180352);
    u16* VtG    = (u16*)(ws);              // reuses xb/wqkvT after gemm1
    u16* wprojT = (u16*)(ws + 17719296);
    u16* qkv    = (u16*)(ws + 18898944);
    u16* aout   = (u16*)(ws + 61440000);

    f32_to_bf16<<<6924, 256, 0, stream>>>(x, xb, 7090176);
    transpose_f32_bf16<<<dim3(72, 24), 256, 0, stream>>>(w_qkv, wqkvT, 768, 2304);
    transpose_f32_bf16<<<dim3(24, 24), 256, 0, stream>>>(w_proj, wprojT, 768, 768);
    gemm_bt<false><<<dim3(73, 18), 256, 0, stream>>>(xb, wqkvT, b_qkv, qkv, 9232, 2304, 768);
    rope_qk<<<6912, 256, 0, stream>>>(qkv, cosp, sinp);
    transpose_v<<<dim3(20, 2, 192), 256, 0, stream>>>(qkv, VtG);
    attn2<<<dim3(10, 192), 256, 0, stream>>>(qkv, VtG, aout);
    gemm_bt<true><<<dim3(73, 6), 256, 0, stream>>>(aout, wprojT, b_proj, out, 9232, 768, 768);
}